// Round 4
// baseline (144.248 us; speedup 1.0000x reference)
//
#include <hip/hip_runtime.h>
#include <hip/hip_bf16.h>
#include <math.h>

#define FEAT 384
#define FFN  768
#define ZDIM 384
#define HID  192
#define BB   4
#define NN   128
#define BN   (BB*NN)   // 512 rows

__device__ __forceinline__ float gelu_exact(float x) {
    return 0.5f * x * (1.0f + erff(x * 0.70710678118654752440f));
}

__device__ __forceinline__ float bflo(unsigned u) { return __uint_as_float(u << 16); }
__device__ __forceinline__ float bfhi(unsigned u) { return __uint_as_float(u & 0xFFFF0000u); }

template<bool F32>
__device__ __forceinline__ float ldg(const void* p, int i) {
    if constexpr (F32) return ((const float*)p)[i];
    return __uint_as_float(((unsigned)((const unsigned short*)p)[i]) << 16);
}
template<bool F32>
__device__ __forceinline__ void stg(void* p, size_t i, float v) {
    if constexpr (F32) ((float*)p)[i] = v;
    else ((__hip_bfloat16*)p)[i] = __float2bfloat16(v);
}

// 4-element weight vector: 16B load (fp32) / 8B load (bf16)
template<bool F32> struct V4;
template<> struct V4<true> {
    float4 a;
    __device__ __forceinline__ void load(const void* p, size_t off) {
        a = *(const float4*)((const float*)p + off);
    }
    __device__ __forceinline__ float g(int i) const { return (&a.x)[i]; }
};
template<> struct V4<false> {
    uint2 u;
    __device__ __forceinline__ void load(const void* p, size_t off) {
        u = *(const uint2*)((const unsigned short*)p + off);
    }
    __device__ __forceinline__ float g(int i) const {
        const unsigned w = (&u.x)[i >> 1];
        return (i & 1) ? bfhi(w) : bflo(w);
    }
};

__device__ __forceinline__ bool is_f32(const void* ln_w) {
    return ((const unsigned short*)ln_w)[0] == 0;
}

// ---- block reductions over 384 threads (6 wave64) ----
__device__ __forceinline__ float block_sum(float v, float* sm) {
    for (int o = 32; o > 0; o >>= 1) v += __shfl_down(v, o, 64);
    const int lane = threadIdx.x & 63, w = threadIdx.x >> 6;
    __syncthreads();
    if (lane == 0) sm[w] = v;
    __syncthreads();
    return sm[0] + sm[1] + sm[2] + sm[3] + sm[4] + sm[5];
}
__device__ __forceinline__ float block_max(float v, float* sm) {
    for (int o = 32; o > 0; o >>= 1) v = fmaxf(v, __shfl_down(v, o, 64));
    const int lane = threadIdx.x & 63, w = threadIdx.x >> 6;
    __syncthreads();
    if (lane == 0) sm[w] = v;
    __syncthreads();
    return fmaxf(fmaxf(fmaxf(sm[0], sm[1]), fmaxf(sm[2], sm[3])), fmaxf(sm[4], sm[5]));
}
// 8-wide block sum (one barrier pair for 8 values); sm must hold 48 floats
__device__ __forceinline__ void block_sum8(const float v[8], float* sm, float out[8]) {
    float tv[8];
    #pragma unroll
    for (int n = 0; n < 8; n++) tv[n] = v[n];
    for (int o = 32; o > 0; o >>= 1) {
        #pragma unroll
        for (int n = 0; n < 8; n++) tv[n] += __shfl_down(tv[n], o, 64);
    }
    const int lane = threadIdx.x & 63, w = threadIdx.x >> 6;
    __syncthreads();
    if (lane == 0) {
        #pragma unroll
        for (int n = 0; n < 8; n++) sm[n * 6 + w] = tv[n];
    }
    __syncthreads();
    #pragma unroll
    for (int n = 0; n < 8; n++)
        out[n] = sm[n*6] + sm[n*6+1] + sm[n*6+2] + sm[n*6+3] + sm[n*6+4] + sm[n*6+5];
}

// Shared pool (floats): xs 0 (1536), zs 1536 (1536), hid 3072 (768),
// gh 3840 (192) [contiguous after hid => 5th GEMM row], part 4032 (5760),
// sm 9792 (48). Total 9840 = 39.4 KB.
#define SM_TOTAL 9840

// Generic GEMM helper, 3-deep rotating weight staging, float4 LDS activation
// reads. M rows from LDS (in[m*ldin + k]), 4 cols/thread, K-chunk KCH at kb.
template<bool F32, int KCH, int M>
__device__ __forceinline__ void gemmMx4(
    const void* __restrict__ W, int ldw, int c0, int kb,
    const float* __restrict__ in, int ldin, float acc[M][4])
{
    constexpr int NB = KCH / 8;
    V4<F32> buf[3][8];
    #pragma unroll
    for (int j = 0; j < 8; j++) buf[0][j].load(W, (size_t)(kb + j) * ldw + c0);
    if (NB > 1) {
        #pragma unroll
        for (int j = 0; j < 8; j++) buf[1][j].load(W, (size_t)(kb + 8 + j) * ldw + c0);
    }
    #pragma unroll
    for (int b = 0; b < NB; b++) {
        const int cur = b % 3;
        if (b + 2 < NB) {
            const int nxt = (b + 2) % 3;
            #pragma unroll
            for (int j = 0; j < 8; j++)
                buf[nxt][j].load(W, (size_t)(kb + (b + 2) * 8 + j) * ldw + c0);
        }
        #pragma unroll
        for (int m = 0; m < M; m++) {
            const float4 x0 = *(const float4*)(in + m * ldin + kb + b * 8);
            const float4 x1 = *(const float4*)(in + m * ldin + kb + b * 8 + 4);
            const float xv[8] = {x0.x, x0.y, x0.z, x0.w, x1.x, x1.y, x1.z, x1.w};
            #pragma unroll
            for (int j = 0; j < 8; j++) {
                #pragma unroll
                for (int i = 0; i < 4; i++)
                    acc[m][i] = fmaf(xv[j], buf[cur][j].g(i), acc[m][i]);
            }
        }
    }
}

// ============ Type A: quad q — U z-half -> LN -> enc -> dec -> dots ============
template<bool F32>
__device__ void bodyA(float* S, int q,
    const void* __restrict__ x, const void* __restrict__ U_w,
    const void* __restrict__ U_b, const void* __restrict__ ln_w,
    const void* __restrict__ ln_b, const void* __restrict__ enc_w,
    const void* __restrict__ enc_b, const void* __restrict__ dec_w,
    const void* __restrict__ dec_b,
    float* __restrict__ d0, float* __restrict__ diag)
{
    const int rb = 4 * q;
    const int t = threadIdx.x;
    float* xs = S;          // 4 x 384
    float* zs = S + 1536;   // 4 x 384
    float* hid = S + 3072;  // 4 x 192  (+ gh right after = 5th row)
    float* gh = S + 3840;   // 192
    float* part = S + 4032; // up to 5760
    float* sm = S + 9792;   // 48

    #pragma unroll
    for (int m = 0; m < 4; m++) xs[m * 384 + t] = ldg<F32>(x, (rb + m) * FEAT + t);
    if (t < HID) gh[t] = gelu_exact(ldg<F32>(enc_b, t));
    __syncthreads();

    // ---- U z-half: cg=t%96 -> 4 cols (global 384+4cg); kh=t/96 -> K 96kh..+96 ----
    const int cg = t % 96, kh = t / 96;
    const int cL = 4 * cg, cG = ZDIM + cL, kb = 96 * kh;
    float acc[4][4] = {};
    gemmMx4<F32, 96, 4>(U_w, FFN, cG, kb, xs, 384, acc);
    if (kh > 0) {
        float* p = &part[(kh - 1) * 1536 + cg];
        #pragma unroll
        for (int m = 0; m < 4; m++)
            #pragma unroll
            for (int i = 0; i < 4; i++) p[(m * 4 + i) * 96] = acc[m][i];
    }
    __syncthreads();

    float hv[4][4];
    float sv[8] = {};
    if (kh == 0) {
        #pragma unroll
        for (int i = 0; i < 4; i++) {
            const float ub = ldg<F32>(U_b, cG + i);
            #pragma unroll
            for (int m = 0; m < 4; m++) {
                float v = acc[m][i] + ub
                        + part[(m * 4 + i) * 96 + cg]
                        + part[1536 + (m * 4 + i) * 96 + cg]
                        + part[3072 + (m * 4 + i) * 96 + cg];
                v = gelu_exact(v);
                hv[m][i] = v;
                sv[m] += v;           // s1
                sv[4 + m] += v * v;   // s2
            }
        }
    }
    float SS[8];
    block_sum8(sv, sm, SS);   // one barrier pair for both moments
    if (kh == 0) {
        #pragma unroll
        for (int m = 0; m < 4; m++) {
            const float mu = SS[m] * (1.0f / ZDIM);
            const float rs = rsqrtf(SS[4 + m] * (1.0f / ZDIM) - mu * mu + 1e-5f);
            #pragma unroll
            for (int i = 0; i < 4; i++) {
                const int zc = cL + i;
                zs[m * 384 + zc] = (hv[m][i] - mu) * rs * ldg<F32>(ln_w, zc) + ldg<F32>(ln_b, zc);
            }
        }
    }
    __syncthreads();

    // ---- encoder: cgE=t%48 -> 4 cols of 192; khE=t/48 -> K 48khE..+48 ----
    {
        const int cgE = t % 48, khE = t / 48;
        const int cE = 4 * cgE, kbE = 48 * khE;
        float ea[4][4] = {};
        gemmMx4<F32, 48, 4>(enc_w, HID, cE, kbE, zs, 384, ea);
        if (khE > 0) {
            float* p = &part[(khE - 1) * 768 + cgE];
            #pragma unroll
            for (int m = 0; m < 4; m++)
                #pragma unroll
                for (int i = 0; i < 4; i++) p[(m * 4 + i) * 48] = ea[m][i];
        }
        __syncthreads();
        if (khE == 0) {
            #pragma unroll
            for (int i = 0; i < 4; i++) {
                const float ebv = ldg<F32>(enc_b, cE + i);
                #pragma unroll
                for (int m = 0; m < 4; m++) {
                    float v = ea[m][i] + ebv;
                    #pragma unroll
                    for (int kk = 0; kk < 7; kk++)
                        v += part[kk * 768 + (m * 4 + i) * 48 + cgE];
                    hid[m * 192 + cE + i] = gelu_exact(v);
                }
            }
        }
        __syncthreads();
    }

    // ---- decoder: 5-row GEMM (4 hid rows + gh as row 4) ----
    {
        const int cgD = t % 96, khD = t / 96;
        const int cD = 4 * cgD, kbD = 48 * khD;
        float da[5][4] = {};
        gemmMx4<F32, 48, 5>(dec_w, ZDIM, cD, kbD, hid, 192, da);
        if (khD > 0) {
            float* p = &part[(khD - 1) * 1920 + cgD];
            #pragma unroll
            for (int m = 0; m < 5; m++)
                #pragma unroll
                for (int i = 0; i < 4; i++) p[(m * 4 + i) * 96] = da[m][i];
        }
        __syncthreads();
        float dv[8] = {};
        if (khD == 0) {
            #pragma unroll
            for (int i = 0; i < 4; i++) {
                const int c = cD + i;
                const float dbv = ldg<F32>(dec_b, c);
                float vc = da[4][i] + dbv;
                #pragma unroll
                for (int kk = 0; kk < 3; kk++)
                    vc += part[kk * 1920 + (16 + i) * 96 + cgD];
                #pragma unroll
                for (int m = 0; m < 4; m++) {
                    float v = da[m][i] + dbv;
                    #pragma unroll
                    for (int kk = 0; kk < 3; kk++)
                        v += part[kk * 1920 + (m * 4 + i) * 96 + cgD];
                    const float zv = zs[m * 384 + c];
                    dv[m] = fmaf(v, zv, dv[m]);        // diag partial
                    dv[4 + m] = fmaf(vc, zv, dv[4 + m]); // d0 partial
                }
            }
        }
        float DD8[8];
        block_sum8(dv, sm, DD8);   // one barrier pair for both dot sets
        if (t == 0) {
            #pragma unroll
            for (int m = 0; m < 4; m++) { diag[rb + m] = DD8[m]; d0[rb + m] = DD8[4 + m]; }
        }
    }
}

// ============ Type B: quad q — U xh-half -> Y = xh @ V_w ============
template<bool F32>
__device__ void bodyB(float* S, int q,
    const void* __restrict__ x, const void* __restrict__ U_w,
    const void* __restrict__ U_b, const void* __restrict__ V_w,
    float* __restrict__ Y)
{
    const int rb = 4 * q;
    const int t = threadIdx.x;
    float* xs = S;          // 4 x 384
    float* zs = S + 1536;   // 4 x 384 (xh)
    float* part = S + 4032;

    #pragma unroll
    for (int m = 0; m < 4; m++) xs[m * 384 + t] = ldg<F32>(x, (rb + m) * FEAT + t);
    __syncthreads();

    const int cg = t % 96, kh = t / 96;
    const int cL = 4 * cg, kb = 96 * kh;
    float acc[4][4] = {};
    gemmMx4<F32, 96, 4>(U_w, FFN, cL, kb, xs, 384, acc);
    if (kh > 0) {
        float* p = &part[(kh - 1) * 1536 + cg];
        #pragma unroll
        for (int m = 0; m < 4; m++)
            #pragma unroll
            for (int i = 0; i < 4; i++) p[(m * 4 + i) * 96] = acc[m][i];
    }
    __syncthreads();
    if (kh == 0) {
        #pragma unroll
        for (int i = 0; i < 4; i++) {
            const float ub = ldg<F32>(U_b, cL + i);
            #pragma unroll
            for (int m = 0; m < 4; m++) {
                float v = acc[m][i] + ub
                        + part[(m * 4 + i) * 96 + cg]
                        + part[1536 + (m * 4 + i) * 96 + cg]
                        + part[3072 + (m * 4 + i) * 96 + cg];
                zs[m * 384 + cL + i] = gelu_exact(v);
            }
        }
    }
    __syncthreads();

    // V: same thread mapping; K = 384 full
    float ya[4][4] = {};
    gemmMx4<F32, 96, 4>(V_w, FEAT, cL, kb, zs, 384, ya);
    if (kh > 0) {
        float* p = &part[(kh - 1) * 1536 + cg];
        #pragma unroll
        for (int m = 0; m < 4; m++)
            #pragma unroll
            for (int i = 0; i < 4; i++) p[(m * 4 + i) * 96] = ya[m][i];
    }
    __syncthreads();
    if (kh == 0) {
        #pragma unroll
        for (int m = 0; m < 4; m++) {
            float o[4];
            #pragma unroll
            for (int i = 0; i < 4; i++) {
                o[i] = ya[m][i]
                     + part[(m * 4 + i) * 96 + cg]
                     + part[1536 + (m * 4 + i) * 96 + cg]
                     + part[3072 + (m * 4 + i) * 96 + cg];
            }
            *(float4*)(Y + (size_t)(rb + m) * FEAT + cL) = make_float4(o[0], o[1], o[2], o[3]);
        }
    }
}

// ============ combine chunk (run by last 16 arrivals of each batch) ============
// out_i = (baseY + (ed_i - e0_i) * Y_i) / (S - e0_i + ed_i) + V_b
template<bool F32>
__device__ void combine_chunk(float* S, int b, int cc,
    const float* __restrict__ d0, const float* __restrict__ diag,
    const float* __restrict__ Y,
    const void* __restrict__ V_b, void* __restrict__ out)
{
    const int t = threadIdx.x;
    const int c = t % 24, qq = t / 24;      // 16 row-groups of 8 rows
    float* e0s   = S;          // 128
    float* eds   = S + 128;    // 128
    float* bp    = S + 256;    // 16*24
    float* baseY = S + 640;    // 24
    float* smc   = S + 664;    // 12

    float d0v = -INFINITY, dgv = -INFINITY;
    if (t < NN) { d0v = d0[b * NN + t]; dgv = diag[b * NN + t]; }
    const float m = block_max(fmaxf(d0v, dgv), smc);
    float e0v = 0.f;
    if (t < NN) {
        e0v = expf(d0v - m);
        e0s[t] = e0v;
        eds[t] = expf(dgv - m);
    }
    const float Ssum = block_sum(e0v, smc);     // internal syncs publish e0s/eds

    const float* Yb = Y + (size_t)b * NN * FEAT + cc + c;
    const int j0 = 8 * qq;
    float w[8];
    #pragma unroll
    for (int j = 0; j < 8; j++) w[j] = Yb[(size_t)(j0 + j) * FEAT];
    float p = 0.f;
    #pragma unroll
    for (int j = 0; j < 8; j++) p = fmaf(e0s[j0 + j], w[j], p);
    bp[qq * 24 + c] = p;
    __syncthreads();
    if (qq == 0) {
        float s = 0.f;
        #pragma unroll
        for (int g = 0; g < 16; g++) s += bp[g * 24 + c];
        baseY[c] = s;
    }
    __syncthreads();

    const float bY = baseY[c];
    const float vb = ldg<F32>(V_b, cc + c);
    #pragma unroll
    for (int j = 0; j < 8; j++) {
        const int r = j0 + j;
        const float inv = 1.0f / (Ssum - e0s[r] + eds[r]);
        const float val = (bY + (eds[r] - e0s[r]) * w[j]) * inv + vb;
        stg<F32>(out, (size_t)(b * NN + r) * FEAT + cc + c, val);
    }
}

__global__ __launch_bounds__(384) void k_main(
    const void* x, const void* U_w, const void* U_b,
    const void* ln_w, const void* ln_b,
    const void* enc_w, const void* enc_b,
    const void* dec_w, const void* dec_b, const void* V_w,
    const void* V_b,
    float* Y, float* d0, float* diag, int* cnt, void* out)
{
    __shared__ float S[SM_TOTAL];   // single pool for all phases
    const bool f32 = is_f32(ln_w);
    const int type = blockIdx.x & 1;
    const int q = blockIdx.x >> 1;
    if (f32) {
        if (type == 0) bodyA<true >(S, q, x, U_w, U_b, ln_w, ln_b, enc_w, enc_b, dec_w, dec_b, d0, diag);
        else           bodyB<true >(S, q, x, U_w, U_b, V_w, Y);
    } else {
        if (type == 0) bodyA<false>(S, q, x, U_w, U_b, ln_w, ln_b, enc_w, enc_b, dec_w, dec_b, d0, diag);
        else           bodyB<false>(S, q, x, U_w, U_b, V_w, Y);
    }

    // ---- last-arrivals combine: per-batch ticket; tickets 48..63 do chunks ----
    const int b = q >> 5;                       // batch of this worker block
    __threadfence();                            // drain this thread's stores
    __syncthreads();                            // all block stores drained
    if (threadIdx.x == 0) {
        const int tk = __hip_atomic_fetch_add(&cnt[b], 1, __ATOMIC_RELEASE,
                                              __HIP_MEMORY_SCOPE_AGENT);
        ((int*)S)[0] = tk;
    }
    __syncthreads();
    const int tk = ((int*)S)[0];
    if (tk < 48) return;

    if (threadIdx.x == 0) {
        while (__hip_atomic_load(&cnt[b], __ATOMIC_RELAXED,
                                 __HIP_MEMORY_SCOPE_AGENT) < 64)
            __builtin_amdgcn_s_sleep(2);
        (void)__hip_atomic_load(&cnt[b], __ATOMIC_ACQUIRE,
                                __HIP_MEMORY_SCOPE_AGENT);
    }
    __syncthreads();
    __threadfence();                            // acquire-side: invalidate stale lines

    const int cc = (tk - 48) * 24;
    if (f32) combine_chunk<true >(S, b, cc, d0, diag, Y, V_b, out);
    else     combine_chunk<false>(S, b, cc, d0, diag, Y, V_b, out);
}

extern "C" void kernel_launch(void* const* d_in, const int* in_sizes, int n_in,
                              void* d_out, int out_size, void* d_ws, size_t ws_size,
                              hipStream_t stream) {
    const void* x     = d_in[0];
    const void* U_w   = d_in[1];
    const void* U_b   = d_in[2];
    const void* ln_w  = d_in[3];
    const void* ln_b  = d_in[4];
    const void* enc_w = d_in[5];
    const void* enc_b = d_in[6];
    const void* dec_w = d_in[7];
    const void* dec_b = d_in[8];
    const void* V_w   = d_in[9];
    const void* V_b   = d_in[10];

    float* ws   = (float*)d_ws;
    float* Y    = ws;                     // 512*384  (xh @ V_w, no bias)
    float* d0   = Y + (size_t)BN * FEAT;  // 512
    float* diag = d0 + BN;                // 512
    int*   cnt  = (int*)(diag + BN);      // 4 per-batch counters (16B-aligned)

    hipMemsetAsync(cnt, 0, 4 * sizeof(int), stream);
    k_main<<<2 * (BN / 4), 384, 0, stream>>>(x, U_w, U_b, ln_w, ln_b, enc_w, enc_b,
                                             dec_w, dec_b, V_w, V_b,
                                             Y, d0, diag, cnt, d_out);
}

// Round 5
// 103.255 us; speedup vs baseline: 1.3970x; 1.3970x over previous
//
#include <hip/hip_runtime.h>
#include <hip/hip_bf16.h>
#include <math.h>

#define FEAT 384
#define FFN  768
#define ZDIM 384
#define HID  192
#define BB   4
#define NN   128
#define BN   (BB*NN)   // 512 rows
#define MAGIC 0x9E3779B9u

__device__ __forceinline__ float gelu_exact(float x) {
    return 0.5f * x * (1.0f + erff(x * 0.70710678118654752440f));
}

__device__ __forceinline__ float bflo(unsigned u) { return __uint_as_float(u << 16); }
__device__ __forceinline__ float bfhi(unsigned u) { return __uint_as_float(u & 0xFFFF0000u); }

template<bool F32>
__device__ __forceinline__ float ldg(const void* p, int i) {
    if constexpr (F32) return ((const float*)p)[i];
    return __uint_as_float(((unsigned)((const unsigned short*)p)[i]) << 16);
}
template<bool F32>
__device__ __forceinline__ void stg(void* p, size_t i, float v) {
    if constexpr (F32) ((float*)p)[i] = v;
    else ((__hip_bfloat16*)p)[i] = __float2bfloat16(v);
}

// device-coherent (MALL/sc1) scalar access for cross-block data — NO fences
__device__ __forceinline__ void st_dev(float* p, float v) {
    __hip_atomic_store(p, v, __ATOMIC_RELAXED, __HIP_MEMORY_SCOPE_AGENT);
}
__device__ __forceinline__ float ld_dev(const float* p) {
    return __hip_atomic_load(p, __ATOMIC_RELAXED, __HIP_MEMORY_SCOPE_AGENT);
}
__device__ __forceinline__ void st_devu(unsigned* p, unsigned v) {
    __hip_atomic_store(p, v, __ATOMIC_RELAXED, __HIP_MEMORY_SCOPE_AGENT);
}
__device__ __forceinline__ unsigned ld_devu(const unsigned* p) {
    return __hip_atomic_load(p, __ATOMIC_RELAXED, __HIP_MEMORY_SCOPE_AGENT);
}

// 4-element weight vector: 16B load (fp32) / 8B load (bf16)
template<bool F32> struct V4;
template<> struct V4<true> {
    float4 a;
    __device__ __forceinline__ void load(const void* p, size_t off) {
        a = *(const float4*)((const float*)p + off);
    }
    __device__ __forceinline__ float g(int i) const { return (&a.x)[i]; }
};
template<> struct V4<false> {
    uint2 u;
    __device__ __forceinline__ void load(const void* p, size_t off) {
        u = *(const uint2*)((const unsigned short*)p + off);
    }
    __device__ __forceinline__ float g(int i) const {
        const unsigned w = (&u.x)[i >> 1];
        return (i & 1) ? bfhi(w) : bflo(w);
    }
};

__device__ __forceinline__ bool is_f32(const void* ln_w) {
    return ((const unsigned short*)ln_w)[0] == 0;
}

// ---- block reductions over 384 threads (6 wave64) ----
__device__ __forceinline__ float block_sum(float v, float* sm) {
    for (int o = 32; o > 0; o >>= 1) v += __shfl_down(v, o, 64);
    const int lane = threadIdx.x & 63, w = threadIdx.x >> 6;
    __syncthreads();
    if (lane == 0) sm[w] = v;
    __syncthreads();
    return sm[0] + sm[1] + sm[2] + sm[3] + sm[4] + sm[5];
}
__device__ __forceinline__ float block_max(float v, float* sm) {
    for (int o = 32; o > 0; o >>= 1) v = fmaxf(v, __shfl_down(v, o, 64));
    const int lane = threadIdx.x & 63, w = threadIdx.x >> 6;
    __syncthreads();
    if (lane == 0) sm[w] = v;
    __syncthreads();
    return fmaxf(fmaxf(fmaxf(sm[0], sm[1]), fmaxf(sm[2], sm[3])), fmaxf(sm[4], sm[5]));
}
// 8-wide block sum (one barrier pair for 8 values); sm must hold 48 floats
__device__ __forceinline__ void block_sum8(const float v[8], float* sm, float out[8]) {
    float tv[8];
    #pragma unroll
    for (int n = 0; n < 8; n++) tv[n] = v[n];
    for (int o = 32; o > 0; o >>= 1) {
        #pragma unroll
        for (int n = 0; n < 8; n++) tv[n] += __shfl_down(tv[n], o, 64);
    }
    const int lane = threadIdx.x & 63, w = threadIdx.x >> 6;
    __syncthreads();
    if (lane == 0) {
        #pragma unroll
        for (int n = 0; n < 8; n++) sm[n * 6 + w] = tv[n];
    }
    __syncthreads();
    #pragma unroll
    for (int n = 0; n < 8; n++)
        out[n] = sm[n*6] + sm[n*6+1] + sm[n*6+2] + sm[n*6+3] + sm[n*6+4] + sm[n*6+5];
}

// Shared pool (floats): xs 0 (1536), zs 1536 (1536), hid 3072 (768),
// gh 3840 (192) [contiguous after hid => 5th GEMM row], part 4032 (5760),
// sm 9792 (48). Total 9840 = 39.4 KB.
#define SM_TOTAL 9840

// Generic GEMM helper, 3-deep rotating weight staging, float4 LDS activation
// reads. M rows from LDS (in[m*ldin + k]), 4 cols/thread, K-chunk KCH at kb.
template<bool F32, int KCH, int M>
__device__ __forceinline__ void gemmMx4(
    const void* __restrict__ W, int ldw, int c0, int kb,
    const float* __restrict__ in, int ldin, float acc[M][4])
{
    constexpr int NB = KCH / 8;
    V4<F32> buf[3][8];
    #pragma unroll
    for (int j = 0; j < 8; j++) buf[0][j].load(W, (size_t)(kb + j) * ldw + c0);
    if (NB > 1) {
        #pragma unroll
        for (int j = 0; j < 8; j++) buf[1][j].load(W, (size_t)(kb + 8 + j) * ldw + c0);
    }
    #pragma unroll
    for (int b = 0; b < NB; b++) {
        const int cur = b % 3;
        if (b + 2 < NB) {
            const int nxt = (b + 2) % 3;
            #pragma unroll
            for (int j = 0; j < 8; j++)
                buf[nxt][j].load(W, (size_t)(kb + (b + 2) * 8 + j) * ldw + c0);
        }
        #pragma unroll
        for (int m = 0; m < M; m++) {
            const float4 x0 = *(const float4*)(in + m * ldin + kb + b * 8);
            const float4 x1 = *(const float4*)(in + m * ldin + kb + b * 8 + 4);
            const float xv[8] = {x0.x, x0.y, x0.z, x0.w, x1.x, x1.y, x1.z, x1.w};
            #pragma unroll
            for (int j = 0; j < 8; j++) {
                #pragma unroll
                for (int i = 0; i < 4; i++)
                    acc[m][i] = fmaf(xv[j], buf[cur][j].g(i), acc[m][i]);
            }
        }
    }
}

// ============ Type A: quad q — U z-half -> LN -> enc -> dec -> dots ============
template<bool F32>
__device__ void bodyA(float* S, int q,
    const void* __restrict__ x, const void* __restrict__ U_w,
    const void* __restrict__ U_b, const void* __restrict__ ln_w,
    const void* __restrict__ ln_b, const void* __restrict__ enc_w,
    const void* __restrict__ enc_b, const void* __restrict__ dec_w,
    const void* __restrict__ dec_b,
    float* __restrict__ d0, float* __restrict__ diag)
{
    const int rb = 4 * q;
    const int t = threadIdx.x;
    float* xs = S;          // 4 x 384
    float* zs = S + 1536;   // 4 x 384
    float* hid = S + 3072;  // 4 x 192  (+ gh right after = 5th row)
    float* gh = S + 3840;   // 192
    float* part = S + 4032; // up to 5760
    float* sm = S + 9792;   // 48

    #pragma unroll
    for (int m = 0; m < 4; m++) xs[m * 384 + t] = ldg<F32>(x, (rb + m) * FEAT + t);
    if (t < HID) gh[t] = gelu_exact(ldg<F32>(enc_b, t));
    __syncthreads();

    // ---- U z-half: cg=t%96 -> 4 cols (global 384+4cg); kh=t/96 -> K 96kh..+96 ----
    const int cg = t % 96, kh = t / 96;
    const int cL = 4 * cg, cG = ZDIM + cL, kb = 96 * kh;
    float acc[4][4] = {};
    gemmMx4<F32, 96, 4>(U_w, FFN, cG, kb, xs, 384, acc);
    if (kh > 0) {
        float* p = &part[(kh - 1) * 1536 + cg];
        #pragma unroll
        for (int m = 0; m < 4; m++)
            #pragma unroll
            for (int i = 0; i < 4; i++) p[(m * 4 + i) * 96] = acc[m][i];
    }
    __syncthreads();

    float hv[4][4];
    float sv[8] = {};
    if (kh == 0) {
        #pragma unroll
        for (int i = 0; i < 4; i++) {
            const float ub = ldg<F32>(U_b, cG + i);
            #pragma unroll
            for (int m = 0; m < 4; m++) {
                float v = acc[m][i] + ub
                        + part[(m * 4 + i) * 96 + cg]
                        + part[1536 + (m * 4 + i) * 96 + cg]
                        + part[3072 + (m * 4 + i) * 96 + cg];
                v = gelu_exact(v);
                hv[m][i] = v;
                sv[m] += v;           // s1
                sv[4 + m] += v * v;   // s2
            }
        }
    }
    float SS[8];
    block_sum8(sv, sm, SS);   // one barrier pair for both moments
    if (kh == 0) {
        #pragma unroll
        for (int m = 0; m < 4; m++) {
            const float mu = SS[m] * (1.0f / ZDIM);
            const float rs = rsqrtf(SS[4 + m] * (1.0f / ZDIM) - mu * mu + 1e-5f);
            #pragma unroll
            for (int i = 0; i < 4; i++) {
                const int zc = cL + i;
                zs[m * 384 + zc] = (hv[m][i] - mu) * rs * ldg<F32>(ln_w, zc) + ldg<F32>(ln_b, zc);
            }
        }
    }
    __syncthreads();

    // ---- encoder: cgE=t%48 -> 4 cols of 192; khE=t/48 -> K 48khE..+48 ----
    {
        const int cgE = t % 48, khE = t / 48;
        const int cE = 4 * cgE, kbE = 48 * khE;
        float ea[4][4] = {};
        gemmMx4<F32, 48, 4>(enc_w, HID, cE, kbE, zs, 384, ea);
        if (khE > 0) {
            float* p = &part[(khE - 1) * 768 + cgE];
            #pragma unroll
            for (int m = 0; m < 4; m++)
                #pragma unroll
                for (int i = 0; i < 4; i++) p[(m * 4 + i) * 48] = ea[m][i];
        }
        __syncthreads();
        if (khE == 0) {
            #pragma unroll
            for (int i = 0; i < 4; i++) {
                const float ebv = ldg<F32>(enc_b, cE + i);
                #pragma unroll
                for (int m = 0; m < 4; m++) {
                    float v = ea[m][i] + ebv;
                    #pragma unroll
                    for (int kk = 0; kk < 7; kk++)
                        v += part[kk * 768 + (m * 4 + i) * 48 + cgE];
                    hid[m * 192 + cE + i] = gelu_exact(v);
                }
            }
        }
        __syncthreads();
    }

    // ---- decoder: 5-row GEMM (4 hid rows + gh as row 4) ----
    {
        const int cgD = t % 96, khD = t / 96;
        const int cD = 4 * cgD, kbD = 48 * khD;
        float da[5][4] = {};
        gemmMx4<F32, 48, 5>(dec_w, ZDIM, cD, kbD, hid, 192, da);
        if (khD > 0) {
            float* p = &part[(khD - 1) * 1920 + cgD];
            #pragma unroll
            for (int m = 0; m < 5; m++)
                #pragma unroll
                for (int i = 0; i < 4; i++) p[(m * 4 + i) * 96] = da[m][i];
        }
        __syncthreads();
        float dv[8] = {};
        if (khD == 0) {
            #pragma unroll
            for (int i = 0; i < 4; i++) {
                const int c = cD + i;
                const float dbv = ldg<F32>(dec_b, c);
                float vc = da[4][i] + dbv;
                #pragma unroll
                for (int kk = 0; kk < 3; kk++)
                    vc += part[kk * 1920 + (16 + i) * 96 + cgD];
                #pragma unroll
                for (int m = 0; m < 4; m++) {
                    float v = da[m][i] + dbv;
                    #pragma unroll
                    for (int kk = 0; kk < 3; kk++)
                        v += part[kk * 1920 + (m * 4 + i) * 96 + cgD];
                    const float zv = zs[m * 384 + c];
                    dv[m] = fmaf(v, zv, dv[m]);        // diag partial
                    dv[4 + m] = fmaf(vc, zv, dv[4 + m]); // d0 partial
                }
            }
        }
        float DD8[8];
        block_sum8(dv, sm, DD8);   // one barrier pair for both dot sets
        if (t == 0) {
            #pragma unroll
            for (int m = 0; m < 4; m++) {
                st_dev(&diag[rb + m], DD8[m]);
                st_dev(&d0[rb + m],  DD8[4 + m]);
            }
        }
    }
}

// ============ Type B: quad q — U xh-half -> Y = xh @ V_w ============
template<bool F32>
__device__ void bodyB(float* S, int q,
    const void* __restrict__ x, const void* __restrict__ U_w,
    const void* __restrict__ U_b, const void* __restrict__ V_w,
    float* __restrict__ Y)
{
    const int rb = 4 * q;
    const int t = threadIdx.x;
    float* xs = S;          // 4 x 384
    float* zs = S + 1536;   // 4 x 384 (xh)
    float* part = S + 4032;

    #pragma unroll
    for (int m = 0; m < 4; m++) xs[m * 384 + t] = ldg<F32>(x, (rb + m) * FEAT + t);
    __syncthreads();

    const int cg = t % 96, kh = t / 96;
    const int cL = 4 * cg, kb = 96 * kh;
    float acc[4][4] = {};
    gemmMx4<F32, 96, 4>(U_w, FFN, cL, kb, xs, 384, acc);
    if (kh > 0) {
        float* p = &part[(kh - 1) * 1536 + cg];
        #pragma unroll
        for (int m = 0; m < 4; m++)
            #pragma unroll
            for (int i = 0; i < 4; i++) p[(m * 4 + i) * 96] = acc[m][i];
    }
    __syncthreads();
    if (kh == 0) {
        #pragma unroll
        for (int i = 0; i < 4; i++) {
            const float ub = ldg<F32>(U_b, cL + i);
            #pragma unroll
            for (int m = 0; m < 4; m++) {
                float v = acc[m][i] + ub
                        + part[(m * 4 + i) * 96 + cg]
                        + part[1536 + (m * 4 + i) * 96 + cg]
                        + part[3072 + (m * 4 + i) * 96 + cg];
                zs[m * 384 + cL + i] = gelu_exact(v);
            }
        }
    }
    __syncthreads();

    // V: same thread mapping; K = 384 full
    float ya[4][4] = {};
    gemmMx4<F32, 96, 4>(V_w, FEAT, cL, kb, zs, 384, ya);
    if (kh > 0) {
        float* p = &part[(kh - 1) * 1536 + cg];
        #pragma unroll
        for (int m = 0; m < 4; m++)
            #pragma unroll
            for (int i = 0; i < 4; i++) p[(m * 4 + i) * 96] = ya[m][i];
    }
    __syncthreads();
    if (kh == 0) {
        #pragma unroll
        for (int m = 0; m < 4; m++) {
            #pragma unroll
            for (int i = 0; i < 4; i++) {
                const float o = ya[m][i]
                     + part[(m * 4 + i) * 96 + cg]
                     + part[1536 + (m * 4 + i) * 96 + cg]
                     + part[3072 + (m * 4 + i) * 96 + cg];
                st_dev(Y + (size_t)(rb + m) * FEAT + cL + i, o);  // device-coherent
            }
        }
    }
}

// ============ combine chunk (16 static type-B blocks per batch) ============
// out_i = (baseY + (ed_i - e0_i) * Y_i) / (S - e0_i + ed_i) + V_b
template<bool F32>
__device__ void combine_chunk(float* S, int b, int cc,
    const float* __restrict__ d0, const float* __restrict__ diag,
    const float* __restrict__ Y,
    const void* __restrict__ V_b, void* __restrict__ out)
{
    const int t = threadIdx.x;
    const int c = t % 24, qq = t / 24;      // 16 row-groups of 8 rows
    float* e0s   = S;          // 128
    float* eds   = S + 128;    // 128
    float* bp    = S + 256;    // 16*24
    float* baseY = S + 640;    // 24
    float* smc   = S + 664;    // 12

    float d0v = -INFINITY, dgv = -INFINITY;
    if (t < NN) { d0v = ld_dev(&d0[b * NN + t]); dgv = ld_dev(&diag[b * NN + t]); }
    const float m = block_max(fmaxf(d0v, dgv), smc);
    float e0v = 0.f;
    if (t < NN) {
        e0v = expf(d0v - m);
        e0s[t] = e0v;
        eds[t] = expf(dgv - m);
    }
    const float Ssum = block_sum(e0v, smc);     // internal syncs publish e0s/eds

    const float* Yb = Y + (size_t)b * NN * FEAT + cc + c;
    const int j0 = 8 * qq;
    float w[8];
    #pragma unroll
    for (int j = 0; j < 8; j++) w[j] = ld_dev(Yb + (size_t)(j0 + j) * FEAT);
    float p = 0.f;
    #pragma unroll
    for (int j = 0; j < 8; j++) p = fmaf(e0s[j0 + j], w[j], p);
    bp[qq * 24 + c] = p;
    __syncthreads();
    if (qq == 0) {
        float s = 0.f;
        #pragma unroll
        for (int g = 0; g < 16; g++) s += bp[g * 24 + c];
        baseY[c] = s;
    }
    __syncthreads();

    const float bY = baseY[c];
    const float vb = ldg<F32>(V_b, cc + c);
    #pragma unroll
    for (int j = 0; j < 8; j++) {
        const int r = j0 + j;
        const float inv = 1.0f / (Ssum - e0s[r] + eds[r]);
        const float val = (bY + (eds[r] - e0s[r]) * w[j]) * inv + vb;
        stg<F32>(out, (size_t)(b * NN + r) * FEAT + cc + c, val);
    }
}

__global__ __launch_bounds__(384) void k_main(
    const void* x, const void* U_w, const void* U_b,
    const void* ln_w, const void* ln_b,
    const void* enc_w, const void* enc_b,
    const void* dec_w, const void* dec_b, const void* V_w,
    const void* V_b,
    float* Y, float* d0, float* diag, unsigned* flags, void* out)
{
    __shared__ float S[SM_TOTAL];   // single pool for all phases
    const bool f32 = is_f32(ln_w);
    const int type = blockIdx.x & 1;
    const int q = blockIdx.x >> 1;
    if (f32) {
        if (type == 0) bodyA<true >(S, q, x, U_w, U_b, ln_w, ln_b, enc_w, enc_b, dec_w, dec_b, d0, diag);
        else           bodyB<true >(S, q, x, U_w, U_b, V_w, Y);
    } else {
        if (type == 0) bodyA<false>(S, q, x, U_w, U_b, ln_w, ln_b, enc_w, enc_b, dec_w, dec_b, d0, diag);
        else           bodyB<false>(S, q, x, U_w, U_b, V_w, Y);
    }

    // ---- publish: per-wave drain of sc1 stores, then one magic flag ----
    const int b = q >> 5;                       // batch of this block
    unsigned* fb = flags + b * 64;
    asm volatile("s_waitcnt vmcnt(0)" ::: "memory");  // sc1 stores at MALL
    __syncthreads();                                  // all waves drained
    if (threadIdx.x == 0) st_devu(&fb[(q & 31) * 2 + type], MAGIC);

    // ---- combine duty: type-B blocks with (q&31)<16; all blocks co-resident
    //      (grid = 256 = #CUs) so spinning cannot deadlock ----
    if (type != 1 || (q & 31) >= 16) return;
    if (threadIdx.x < 64) {
        while (ld_devu(&fb[threadIdx.x]) != MAGIC)
            __builtin_amdgcn_s_sleep(2);
    }
    __syncthreads();
    asm volatile("" ::: "memory");

    const int cc = (q & 31) * 24;
    if (f32) combine_chunk<true >(S, b, cc, d0, diag, Y, V_b, out);
    else     combine_chunk<false>(S, b, cc, d0, diag, Y, V_b, out);
}

extern "C" void kernel_launch(void* const* d_in, const int* in_sizes, int n_in,
                              void* d_out, int out_size, void* d_ws, size_t ws_size,
                              hipStream_t stream) {
    const void* x     = d_in[0];
    const void* U_w   = d_in[1];
    const void* U_b   = d_in[2];
    const void* ln_w  = d_in[3];
    const void* ln_b  = d_in[4];
    const void* enc_w = d_in[5];
    const void* enc_b = d_in[6];
    const void* dec_w = d_in[7];
    const void* dec_b = d_in[8];
    const void* V_w   = d_in[9];
    const void* V_b   = d_in[10];

    float*    ws    = (float*)d_ws;
    float*    Y     = ws;                     // 512*384  (xh @ V_w, no bias)
    float*    d0    = Y + (size_t)BN * FEAT;  // 512
    float*    diag  = d0 + BN;                // 512
    unsigned* flags = (unsigned*)(diag + BN); // 4*64 magic flags (no init needed)

    k_main<<<2 * (BN / 4), 384, 0, stream>>>(x, U_w, U_b, ln_w, ln_b, enc_w, enc_b,
                                             dec_w, dec_b, V_w, V_b,
                                             Y, d0, diag, flags, d_out);
}